// Round 15
// baseline (463.566 us; speedup 1.0000x reference)
//
#include <hip/hip_runtime.h>
#include <hip/hip_cooperative_groups.h>
#include <math.h>

namespace cgrp = cooperative_groups;

#define N_NODES 50000
#define E_EDGES 800000
#define NEG_SLOPE 0.2f
#define BN_EPS 1e-5f
#define NWAVES 8192   // persistent waves in k_node (2048 blocks x 4 waves)
#define LDB 132       // padded k-stride of B in LDS (bf16 elems)
#define NB_SCAN 196   // ceil(50000/256)
#define NB_PROJ 782   // ceil(50000/64)
#define NB_CNT 3125   // ceil(800000/256)
#define NB_BNF 1024   // cooperative bn+final blocks (4/CU, co-resident)

using bf4 = __attribute__((ext_vector_type(4))) short;
using bf8 = __attribute__((ext_vector_type(8))) short;
using f32x4 = __attribute__((ext_vector_type(4))) float;
using half2v = __attribute__((ext_vector_type(2))) _Float16;

__device__ __forceinline__ unsigned short f2b(float f) {
  unsigned u = __float_as_uint(f);
  return (unsigned short)((u + 0x7FFFu + ((u >> 16) & 1u)) >> 16);  // RNE
}
__device__ __forceinline__ float b2f_lo(unsigned u) {
  return __uint_as_float(u << 16);
}
__device__ __forceinline__ float b2f_hi(unsigned u) {
  return __uint_as_float(u & 0xFFFF0000u);
}

// ---- Kernel 1 (merged): blocks [0,NB_PROJ) compute [xl|xr] = x@[W_l|W_r]
// via bf16 MFMA; blocks [NB_PROJ, NB_PROJ+NB_CNT) count in-degree and convert
// edge_attr to f16 (edge order). The two roles overlap compute vs memory.
__global__ __launch_bounds__(256) void k_projcnt(
    const float* __restrict__ x, const float* __restrict__ Wl,
    const float* __restrict__ Wr, unsigned short* __restrict__ xlb,
    unsigned short* __restrict__ xrb, const int* __restrict__ ei,
    const float* __restrict__ ea, int* __restrict__ deg,
    int4* __restrict__ eah) {
  const int t = threadIdx.x;

  if (blockIdx.x >= NB_PROJ) {
    // ---- count + edge_attr f16 conversion role ----
    int e = (blockIdx.x - NB_PROJ) * 256 + t;
    if (e >= E_EDGES) return;
    atomicAdd(&deg[ei[E_EDGES + e]], 1);
    const float4* r = (const float4*)(ea + (size_t)e * 16);
    float4 v0 = r[0], v1 = r[1], v2 = r[2], v3 = r[3];
    union {
      half2v h[8];
      int4 q[2];
    } u;
    u.h[0] = (half2v){(_Float16)v0.x, (_Float16)v0.y};
    u.h[1] = (half2v){(_Float16)v0.z, (_Float16)v0.w};
    u.h[2] = (half2v){(_Float16)v1.x, (_Float16)v1.y};
    u.h[3] = (half2v){(_Float16)v1.z, (_Float16)v1.w};
    u.h[4] = (half2v){(_Float16)v2.x, (_Float16)v2.y};
    u.h[5] = (half2v){(_Float16)v2.z, (_Float16)v2.w};
    u.h[6] = (half2v){(_Float16)v3.x, (_Float16)v3.y};
    u.h[7] = (half2v){(_Float16)v3.z, (_Float16)v3.w};
    eah[(size_t)e * 2] = u.q[0];
    eah[(size_t)e * 2 + 1] = u.q[1];
    return;
  }

  // ---- projection role ----
  __shared__ __align__(16) unsigned short blds[256 * LDB];
#pragma unroll
  for (int s = 0; s < 32; ++s) {
    int i4 = s * 256 + t;            // float4 index into [128][256]
    int k = (i4 * 4) >> 8;
    int colb = (i4 * 4) & 255;
    float4 w = (colb < 128) ? *(const float4*)(Wl + k * 128 + colb)
                            : *(const float4*)(Wr + k * 128 + (colb - 128));
    blds[(colb + 0) * LDB + k] = f2b(w.x);
    blds[(colb + 1) * LDB + k] = f2b(w.y);
    blds[(colb + 2) * LDB + k] = f2b(w.z);
    blds[(colb + 3) * LDB + k] = f2b(w.w);
  }
  __syncthreads();

  const int wave = t >> 6, lane = t & 63;
  const int f = lane & 15;      // row-in-tile for A, col-in-tile for B
  const int g = lane >> 4;      // k-slot group
  const int r0 = blockIdx.x * 64 + wave * 16;
  const int row = r0 + f;
  const bool rok = row < N_NODES;

  f32x4 acc[16];
#pragma unroll
  for (int c = 0; c < 16; ++c) acc[c] = (f32x4){0.f, 0.f, 0.f, 0.f};

#pragma unroll
  for (int ks = 0; ks < 4; ++ks) {
    bf8 a;
    if (rok) {
      const float* ap = x + (size_t)row * 128 + ks * 32 + g * 8;
      float4 a0 = *(const float4*)(ap);
      float4 a1 = *(const float4*)(ap + 4);
      a = (bf8){(short)f2b(a0.x), (short)f2b(a0.y), (short)f2b(a0.z),
                (short)f2b(a0.w), (short)f2b(a1.x), (short)f2b(a1.y),
                (short)f2b(a1.z), (short)f2b(a1.w)};
    } else {
      a = (bf8){0, 0, 0, 0, 0, 0, 0, 0};
    }
#pragma unroll
    for (int c = 0; c < 16; ++c) {
      const bf4* bp =
          (const bf4*)(blds + (c * 16 + f) * LDB + ks * 32 + g * 8);
      bf8 b = __builtin_shufflevector(bp[0], bp[1], 0, 1, 2, 3, 4, 5, 6, 7);
      acc[c] = __builtin_amdgcn_mfma_f32_16x16x32_bf16(a, b, acc[c], 0, 0, 0);
    }
  }

  // epilogue: col = c*16 + f; c<8 -> xlb, c>=8 -> xrb (both bf16)
#pragma unroll
  for (int c = 0; c < 16; ++c) {
    unsigned short* dst = (c < 8) ? xlb : xrb;
    int cc = (c * 16 + f) & 127;
#pragma unroll
    for (int r = 0; r < 4; ++r) {
      int rr = r0 + g * 4 + r;
      if (rr < N_NODES) dst[(size_t)rr * 128 + cc] = f2b(acc[c][r]);
    }
  }
}

// ---- CSR build: fused 3-phase scan (cooperative, 196 blocks).
// Phase 1 = per-block exclusive scan; grid.sync; phase 2 = block 0 scans the
// 196 block sums; grid.sync; phase 3 = add block offsets (offs final).
// Also zeroes the BN accumulators (block 0) for k_bnfinal.
__global__ __launch_bounds__(256) void k_scan_coop(const int* __restrict__ deg,
                                                   int* __restrict__ offs,
                                                   int* __restrict__ bsum,
                                                   float* __restrict__ bn0) {
  cgrp::grid_group grid = cgrp::this_grid();
  __shared__ int s[256];
  const int t = threadIdx.x;
  const int idx = blockIdx.x * 256 + t;
  if (blockIdx.x == 0) bn0[t] = 0.f;  // bnsum[128]+bnsq[128]

  int v = (idx < N_NODES) ? deg[idx] : 0;
  s[t] = v;
  __syncthreads();
  int acc = v;
#pragma unroll
  for (int off = 1; off < 256; off <<= 1) {
    int u = (t >= off) ? s[t - off] : 0;
    __syncthreads();
    acc += u;
    s[t] = acc;
    __syncthreads();
  }
  if (idx < N_NODES) offs[idx] = acc - v;  // exclusive within block
  if (t == 255) bsum[blockIdx.x] = acc;

  grid.sync();

  if (blockIdx.x == 0) {
    int bv = (t < NB_SCAN) ? bsum[t] : 0;
    s[t] = bv;
    __syncthreads();
    int bacc = bv;
#pragma unroll
    for (int off = 1; off < 256; off <<= 1) {
      int u = (t >= off) ? s[t - off] : 0;
      __syncthreads();
      bacc += u;
      s[t] = bacc;
      __syncthreads();
    }
    if (t < NB_SCAN) bsum[t] = bacc - bv;  // exclusive
  }

  grid.sync();

  if (idx < N_NODES) offs[idx] += bsum[blockIdx.x];
}

// ---- CSR build: scatter (src,eid) into dst order (8B per edge) ----
__global__ __launch_bounds__(256) void k_fill(const int* __restrict__ ei,
                                              const int* __restrict__ offs,
                                              int* __restrict__ cur,
                                              int2* __restrict__ se) {
  int e = blockIdx.x * 256 + threadIdx.x;
  if (e >= E_EDGES) return;
  int d = ei[E_EDGES + e];
  int p = offs[d] + atomicAdd(&cur[d], 1);
  se[p] = make_int2(ei[e], e);
}

// ---- per-edge score: f16 dot2 edge projection + leaky + dot + reduce ----
__device__ __forceinline__ float fscore16(const half2v* eav,
                                          const half2v* we0h,
                                          const half2v* we1h, float xrx,
                                          float xry, float ax, float ay,
                                          float xlx, float xly) {
  float xe0 = 0.f, xe1 = 0.f;
#pragma unroll
  for (int k = 0; k < 8; ++k) {
#if __has_builtin(__builtin_amdgcn_fdot2)
    xe0 = __builtin_amdgcn_fdot2(eav[k], we0h[k], xe0, false);
    xe1 = __builtin_amdgcn_fdot2(eav[k], we1h[k], xe1, false);
#else
    xe0 += (float)eav[k][0] * (float)we0h[k][0] +
           (float)eav[k][1] * (float)we0h[k][1];
    xe1 += (float)eav[k][0] * (float)we1h[k][0] +
           (float)eav[k][1] * (float)we1h[k][1];
#endif
  }
  float v0 = xlx + xrx + xe0;
  float v1 = xly + xry + xe1;
  v0 = v0 > 0.f ? v0 : NEG_SLOPE * v0;
  v1 = v1 > 0.f ? v1 : NEG_SLOPE * v1;
  float p = v0 * ax + v1 * ay;
  p += __shfl_xor(p, 1);
  p += __shfl_xor(p, 2);
  p += __shfl_xor(p, 4);
  p += __shfl_xor(p, 8);
  return p;
}

// online-softmax update: BRANCHLESS (r10-proven). r11's branchy defer-max
// regressed 105->167us (divergence). Do not reintroduce the branch.
#define UPD(p, xx, xy)              \
  {                                 \
    float mn = fmaxf(m, (p));       \
    float sc = __expf(m - mn);      \
    float pe = __expf((p)-mn);      \
    den = den * sc + pe;            \
    a0 = a0 * sc + pe * (xx);       \
    a1 = a1 * sc + pe * (xy);       \
    m = mn;                         \
  }

// ---- Fused per-dst kernel: PERSISTENT wave-per-node, edge loop x4 ----
// r14-EXACT. Saturated: x4 unroll neutral vs x2; VALUBusy ~64%; keep lean —
// no LDS/barrier/fused-BN (r11/r12 proved those stall it, 105->158us).
__global__ __launch_bounds__(256, 8) void k_node(
    const unsigned short* __restrict__ xlb,
    const unsigned short* __restrict__ xrb, const int2* __restrict__ se,
    const int4* __restrict__ eah, const float* __restrict__ We,
    const float* __restrict__ att, const int* __restrict__ offs,
    const int* __restrict__ deg, float* __restrict__ out) {
  const int wid = __builtin_amdgcn_readfirstlane(
      (int)((blockIdx.x * 256 + threadIdx.x) >> 6));
  const int lane = threadIdx.x & 63;
  const int c0 = lane * 2;

  // hoist W_e columns as f16 pairs (16 VGPR) and att once per wave
  half2v we0h[8], we1h[8];
#pragma unroll
  for (int j = 0; j < 8; ++j) {
    float2 wa = *(const float2*)(We + (2 * j) * 128 + c0);
    float2 wb = *(const float2*)(We + (2 * j + 1) * 128 + c0);
    we0h[j] = (half2v){(_Float16)wa.x, (_Float16)wb.x};
    we1h[j] = (half2v){(_Float16)wa.y, (_Float16)wb.y};
  }
  float2 aw = *(const float2*)(att + c0);

  for (int d = wid; d < N_NODES; d += NWAVES) {
    const int base = __builtin_amdgcn_readfirstlane(offs[d]);
    const int n = __builtin_amdgcn_readfirstlane(deg[d]);
    unsigned ur = *(const unsigned*)(xrb + (size_t)d * 128 + c0);
    float xrx = b2f_lo(ur), xry = b2f_hi(ur);

    float m = -INFINITY, den = 0.f, a0 = 0.f, a1 = 0.f;
    int i = 0;
    for (; i + 4 <= n; i += 4) {
      int2 q0 = se[base + i];
      int2 q1 = se[base + i + 1];
      int2 q2 = se[base + i + 2];
      int2 q3 = se[base + i + 3];
      int s0 = __builtin_amdgcn_readfirstlane(q0.x);
      int s1 = __builtin_amdgcn_readfirstlane(q1.x);
      int s2 = __builtin_amdgcn_readfirstlane(q2.x);
      int s3 = __builtin_amdgcn_readfirstlane(q3.x);
      int e0 = __builtin_amdgcn_readfirstlane(q0.y);
      int e1 = __builtin_amdgcn_readfirstlane(q1.y);
      int e2 = __builtin_amdgcn_readfirstlane(q2.y);
      int e3 = __builtin_amdgcn_readfirstlane(q3.y);
      union {
        int4 q[8];
        half2v h[32];
      } u;
      u.q[0] = eah[(size_t)e0 * 2];
      u.q[1] = eah[(size_t)e0 * 2 + 1];
      u.q[2] = eah[(size_t)e1 * 2];
      u.q[3] = eah[(size_t)e1 * 2 + 1];
      u.q[4] = eah[(size_t)e2 * 2];
      u.q[5] = eah[(size_t)e2 * 2 + 1];
      u.q[6] = eah[(size_t)e3 * 2];
      u.q[7] = eah[(size_t)e3 * 2 + 1];
      unsigned uA = *(const unsigned*)(xlb + (size_t)s0 * 128 + c0);
      unsigned uB = *(const unsigned*)(xlb + (size_t)s1 * 128 + c0);
      unsigned uC = *(const unsigned*)(xlb + (size_t)s2 * 128 + c0);
      unsigned uD = *(const unsigned*)(xlb + (size_t)s3 * 128 + c0);
      float xAx = b2f_lo(uA), xAy = b2f_hi(uA);
      float xBx = b2f_lo(uB), xBy = b2f_hi(uB);
      float xCx = b2f_lo(uC), xCy = b2f_hi(uC);
      float xDx = b2f_lo(uD), xDy = b2f_hi(uD);
      float pA = fscore16(u.h, we0h, we1h, xrx, xry, aw.x, aw.y, xAx, xAy);
      float pB =
          fscore16(u.h + 8, we0h, we1h, xrx, xry, aw.x, aw.y, xBx, xBy);
      float pC =
          fscore16(u.h + 16, we0h, we1h, xrx, xry, aw.x, aw.y, xCx, xCy);
      float pD =
          fscore16(u.h + 24, we0h, we1h, xrx, xry, aw.x, aw.y, xDx, xDy);
      UPD(pA, xAx, xAy);
      UPD(pB, xBx, xBy);
      UPD(pC, xCx, xCy);
      UPD(pD, xDx, xDy);
    }
    for (; i < n; ++i) {
      int2 q = se[base + i];
      int s0 = __builtin_amdgcn_readfirstlane(q.x);
      int e0 = __builtin_amdgcn_readfirstlane(q.y);
      union {
        int4 q[2];
        half2v h[8];
      } u;
      u.q[0] = eah[(size_t)e0 * 2];
      u.q[1] = eah[(size_t)e0 * 2 + 1];
      unsigned uv = *(const unsigned*)(xlb + (size_t)s0 * 128 + c0);
      float xx = b2f_lo(uv), xy = b2f_hi(uv);
      float p = fscore16(u.h, we0h, we1h, xrx, xry, aw.x, aw.y, xx, xy);
      UPD(p, xx, xy);
    }

    float inv = (n > 0) ? 1.f / den : 0.f;
    float2 o;
    o.x = a0 * inv;
    o.y = a1 * inv;
    *(float2*)(out + (size_t)d * 128 + c0) = o;
  }
}

// ---- Fused BN stats + BN apply + ELU + residual (cooperative).
// Phase 1: grid-stride partial {sum,sumsq} per channel + LDS reduce +
// atomics. grid.sync. Phase 2: fold stats, grid-stride apply. The second
// read of `out` (25.6 MB) is L3-resident.
__global__ __launch_bounds__(256) void k_bnfinal(
    const float* __restrict__ agg, const float* __restrict__ x,
    float* __restrict__ bnsum, float* __restrict__ bnsq,
    const float* __restrict__ gamma, const float* __restrict__ beta,
    float* __restrict__ out) {
  cgrp::grid_group grid = cgrp::this_grid();
  __shared__ float ls[256][4];
  __shared__ float lq[256][4];
  __shared__ __align__(16) float ssc[128];
  __shared__ __align__(16) float ssh[128];
  const int t = threadIdx.x;
  const int cg_ = t & 31;  // channel group -> channels 4*cg..4*cg+3
  const int rg = t >> 5;   // row group 0..7
  float s0 = 0, s1 = 0, s2 = 0, s3 = 0, q0 = 0, q1 = 0, q2 = 0, q3 = 0;
  for (int r = blockIdx.x * 8 + rg; r < N_NODES; r += NB_BNF * 8) {
    float4 v = ((const float4*)agg)[(size_t)r * 32 + cg_];
    s0 += v.x; s1 += v.y; s2 += v.z; s3 += v.w;
    q0 += v.x * v.x; q1 += v.y * v.y; q2 += v.z * v.z; q3 += v.w * v.w;
  }
  ls[t][0] = s0; ls[t][1] = s1; ls[t][2] = s2; ls[t][3] = s3;
  lq[t][0] = q0; lq[t][1] = q1; lq[t][2] = q2; lq[t][3] = q3;
  __syncthreads();
  if (t < 32) {
#pragma unroll
    for (int g = 1; g < 8; ++g) {
#pragma unroll
      for (int i = 0; i < 4; ++i) {
        ls[t][i] += ls[g * 32 + t][i];
        lq[t][i] += lq[g * 32 + t][i];
      }
    }
#pragma unroll
    for (int i = 0; i < 4; ++i) {
      unsafeAtomicAdd(bnsum + 4 * t + i, ls[t][i]);
      unsafeAtomicAdd(bnsq + 4 * t + i, lq[t][i]);
    }
  }
  __threadfence();
  grid.sync();

  if (t < 128) {
    float mu = bnsum[t] * (1.0f / N_NODES);
    float var = bnsq[t] * (1.0f / N_NODES) - mu * mu;
    float sc = gamma[t] * rsqrtf(var + BN_EPS);
    ssc[t] = sc;
    ssh[t] = beta[t] - mu * sc;
  }
  __syncthreads();
  for (int i4 = blockIdx.x * 256 + t; i4 < N_NODES * 32; i4 += NB_BNF * 256) {
    int cbase = (i4 * 4) & 127;
    float4 v = ((const float4*)agg)[i4];
    float4 xv = ((const float4*)x)[i4];
    float4 sc = *(const float4*)(ssc + cbase);
    float4 sh = *(const float4*)(ssh + cbase);
    float r0 = v.x * sc.x + sh.x;
    float r1 = v.y * sc.y + sh.y;
    float r2 = v.z * sc.z + sh.z;
    float r3 = v.w * sc.w + sh.w;
    r0 = r0 > 0.f ? r0 : expm1f(r0);
    r1 = r1 > 0.f ? r1 : expm1f(r1);
    r2 = r2 > 0.f ? r2 : expm1f(r2);
    r3 = r3 > 0.f ? r3 : expm1f(r3);
    float4 o;
    o.x = r0 + xv.x; o.y = r1 + xv.y; o.z = r2 + xv.z; o.w = r3 + xv.w;
    ((float4*)out)[i4] = o;
  }
}

extern "C" void kernel_launch(void* const* d_in, const int* in_sizes, int n_in,
                              void* d_out, int out_size, void* d_ws,
                              size_t ws_size, hipStream_t stream) {
  const float* x = (const float*)d_in[0];
  const int* ei = (const int*)d_in[1];
  const float* ea = (const float*)d_in[2];
  const float* Wl = (const float*)d_in[3];
  const float* Wr = (const float*)d_in[4];
  const float* We = (const float*)d_in[5];
  const float* att = (const float*)d_in[6];
  // d_in[7] = bias: cancels inside BatchNorm (per-channel constant) -> unused
  const float* gamma = (const float*)d_in[8];
  const float* beta = (const float*)d_in[9];
  float* out = (float*)d_out;

  unsigned short* xlb = (unsigned short*)d_ws;            // N*128 bf16 (12.8M)
  unsigned short* xrb = xlb + (size_t)N_NODES * 128;      // N*128 bf16 (12.8M)
  int* deg = (int*)(xrb + (size_t)N_NODES * 128);         // 50k
  int* offs = deg + N_NODES;                              // 50k
  int* cur = offs + N_NODES;                              // 50k
  int* bsum = cur + N_NODES;                              // 256
  int2* se = (int2*)(bsum + 256);                         // E int2 (6.4M)
  int4* eah = (int4*)(se + E_EDGES);                      // E*32B f16 (25.6M)
  float* bnsum = (float*)(eah + (size_t)E_EDGES * 2);     // 128
  float* bnsq = bnsum + 128;                              // 128

  // zero deg/offs/cur (contiguous) before projcnt's atomics; bnsum/bnsq
  // zeroed inside k_scan_coop (runs before k_bnfinal's atomics)
  hipMemsetAsync(deg, 0, 3 * N_NODES * sizeof(int), stream);

  k_projcnt<<<NB_PROJ + NB_CNT, 256, 0, stream>>>(x, Wl, Wr, xlb, xrb, ei, ea,
                                                  deg, eah);

  {
    void* args[] = {(void*)&deg, (void*)&offs, (void*)&bsum, (void*)&bnsum};
    hipLaunchCooperativeKernel((void*)k_scan_coop, dim3(NB_SCAN), dim3(256),
                               args, 0, stream);
  }

  k_fill<<<(E_EDGES + 255) / 256, 256, 0, stream>>>(ei, offs, cur, se);
  k_node<<<NWAVES / 4, 256, 0, stream>>>(xlb, xrb, se, eah, We, att, offs,
                                         deg, out);

  {
    void* args[] = {(void*)&out,   (void*)&x,    (void*)&bnsum, (void*)&bnsq,
                    (void*)&gamma, (void*)&beta, (void*)&out};
    hipLaunchCooperativeKernel((void*)k_bnfinal, dim3(NB_BNF), dim3(256),
                               args, 0, stream);
  }
}

// Round 16
// 255.743 us; speedup vs baseline: 1.8126x; 1.8126x over previous
//
#include <hip/hip_runtime.h>
#include <math.h>

#define N_NODES 50000
#define E_EDGES 800000
#define NEG_SLOPE 0.2f
#define BN_EPS 1e-5f
#define NWAVES 8192   // persistent waves in k_node (2048 blocks x 4 waves)
#define LDB 132       // padded k-stride of B in LDS (bf16 elems)
#define NB_SCAN 196   // ceil(50000/256)
#define NB_PROJ 782   // ceil(50000/64)
#define NB_CNT 3125   // ceil(800000/256)

using bf4 = __attribute__((ext_vector_type(4))) short;
using bf8 = __attribute__((ext_vector_type(8))) short;
using f32x4 = __attribute__((ext_vector_type(4))) float;
using half2v = __attribute__((ext_vector_type(2))) _Float16;

__device__ __forceinline__ unsigned short f2b(float f) {
  unsigned u = __float_as_uint(f);
  return (unsigned short)((u + 0x7FFFu + ((u >> 16) & 1u)) >> 16);  // RNE
}
__device__ __forceinline__ float b2f_lo(unsigned u) {
  return __uint_as_float(u << 16);
}
__device__ __forceinline__ float b2f_hi(unsigned u) {
  return __uint_as_float(u & 0xFFFF0000u);
}

// ---- Kernel 1 (merged): blocks [0,NB_PROJ) compute [xl|xr] = x@[W_l|W_r]
// via bf16 MFMA; blocks [NB_PROJ, NB_PROJ+NB_CNT) count in-degree and convert
// edge_attr to f16 (edge order). The two roles overlap compute vs memory.
__global__ __launch_bounds__(256) void k_projcnt(
    const float* __restrict__ x, const float* __restrict__ Wl,
    const float* __restrict__ Wr, unsigned short* __restrict__ xlb,
    unsigned short* __restrict__ xrb, const int* __restrict__ ei,
    const float* __restrict__ ea, int* __restrict__ deg,
    int4* __restrict__ eah) {
  const int t = threadIdx.x;

  if (blockIdx.x >= NB_PROJ) {
    // ---- count + edge_attr f16 conversion role ----
    int e = (blockIdx.x - NB_PROJ) * 256 + t;
    if (e >= E_EDGES) return;
    atomicAdd(&deg[ei[E_EDGES + e]], 1);
    const float4* r = (const float4*)(ea + (size_t)e * 16);
    float4 v0 = r[0], v1 = r[1], v2 = r[2], v3 = r[3];
    union {
      half2v h[8];
      int4 q[2];
    } u;
    u.h[0] = (half2v){(_Float16)v0.x, (_Float16)v0.y};
    u.h[1] = (half2v){(_Float16)v0.z, (_Float16)v0.w};
    u.h[2] = (half2v){(_Float16)v1.x, (_Float16)v1.y};
    u.h[3] = (half2v){(_Float16)v1.z, (_Float16)v1.w};
    u.h[4] = (half2v){(_Float16)v2.x, (_Float16)v2.y};
    u.h[5] = (half2v){(_Float16)v2.z, (_Float16)v2.w};
    u.h[6] = (half2v){(_Float16)v3.x, (_Float16)v3.y};
    u.h[7] = (half2v){(_Float16)v3.z, (_Float16)v3.w};
    eah[(size_t)e * 2] = u.q[0];
    eah[(size_t)e * 2 + 1] = u.q[1];
    return;
  }

  // ---- projection role ----
  __shared__ __align__(16) unsigned short blds[256 * LDB];
#pragma unroll
  for (int s = 0; s < 32; ++s) {
    int i4 = s * 256 + t;            // float4 index into [128][256]
    int k = (i4 * 4) >> 8;
    int colb = (i4 * 4) & 255;
    float4 w = (colb < 128) ? *(const float4*)(Wl + k * 128 + colb)
                            : *(const float4*)(Wr + k * 128 + (colb - 128));
    blds[(colb + 0) * LDB + k] = f2b(w.x);
    blds[(colb + 1) * LDB + k] = f2b(w.y);
    blds[(colb + 2) * LDB + k] = f2b(w.z);
    blds[(colb + 3) * LDB + k] = f2b(w.w);
  }
  __syncthreads();

  const int wave = t >> 6, lane = t & 63;
  const int f = lane & 15;      // row-in-tile for A, col-in-tile for B
  const int g = lane >> 4;      // k-slot group
  const int r0 = blockIdx.x * 64 + wave * 16;
  const int row = r0 + f;
  const bool rok = row < N_NODES;

  f32x4 acc[16];
#pragma unroll
  for (int c = 0; c < 16; ++c) acc[c] = (f32x4){0.f, 0.f, 0.f, 0.f};

#pragma unroll
  for (int ks = 0; ks < 4; ++ks) {
    bf8 a;
    if (rok) {
      const float* ap = x + (size_t)row * 128 + ks * 32 + g * 8;
      float4 a0 = *(const float4*)(ap);
      float4 a1 = *(const float4*)(ap + 4);
      a = (bf8){(short)f2b(a0.x), (short)f2b(a0.y), (short)f2b(a0.z),
                (short)f2b(a0.w), (short)f2b(a1.x), (short)f2b(a1.y),
                (short)f2b(a1.z), (short)f2b(a1.w)};
    } else {
      a = (bf8){0, 0, 0, 0, 0, 0, 0, 0};
    }
#pragma unroll
    for (int c = 0; c < 16; ++c) {
      const bf4* bp =
          (const bf4*)(blds + (c * 16 + f) * LDB + ks * 32 + g * 8);
      bf8 b = __builtin_shufflevector(bp[0], bp[1], 0, 1, 2, 3, 4, 5, 6, 7);
      acc[c] = __builtin_amdgcn_mfma_f32_16x16x32_bf16(a, b, acc[c], 0, 0, 0);
    }
  }

  // epilogue: col = c*16 + f; c<8 -> xlb, c>=8 -> xrb (both bf16)
#pragma unroll
  for (int c = 0; c < 16; ++c) {
    unsigned short* dst = (c < 8) ? xlb : xrb;
    int cc = (c * 16 + f) & 127;
#pragma unroll
    for (int r = 0; r < 4; ++r) {
      int rr = r0 + g * 4 + r;
      if (rr < N_NODES) dst[(size_t)rr * 128 + cc] = f2b(acc[c][r]);
    }
  }
}

// ---- CSR build: block-level exclusive scan (multi-block, coalesced).
// NOTE r15: cooperative grid.sync() fusion of the scan / bn+final phases
// regressed 256->464us (1024-block grid.sync spins ~150us+ on 8 XCDs).
// Separate small dispatches are an order of magnitude cheaper here.
__global__ __launch_bounds__(256) void k_scan_blk(const int* __restrict__ deg,
                                                  int* __restrict__ offs,
                                                  int* __restrict__ bsum) {
  __shared__ int s[256];
  int t = threadIdx.x, idx = blockIdx.x * 256 + t;
  int v = (idx < N_NODES) ? deg[idx] : 0;
  s[t] = v;
  __syncthreads();
  int acc = v;
#pragma unroll
  for (int off = 1; off < 256; off <<= 1) {
    int u = (t >= off) ? s[t - off] : 0;
    __syncthreads();
    acc += u;
    s[t] = acc;
    __syncthreads();
  }
  if (idx < N_NODES) offs[idx] = acc - v;  // exclusive within block
  if (t == 255) bsum[blockIdx.x] = acc;
}

// ---- CSR build: scan of block sums (single tiny block over 196) ----
__global__ __launch_bounds__(256) void k_scan_top(int* __restrict__ bsum) {
  __shared__ int s[256];
  int t = threadIdx.x;
  int v = (t < NB_SCAN) ? bsum[t] : 0;
  s[t] = v;
  __syncthreads();
  int acc = v;
#pragma unroll
  for (int off = 1; off < 256; off <<= 1) {
    int u = (t >= off) ? s[t - off] : 0;
    __syncthreads();
    acc += u;
    s[t] = acc;
    __syncthreads();
  }
  if (t < NB_SCAN) bsum[t] = acc - v;  // exclusive
}

// ---- CSR build: add block offsets (offs becomes FINAL here) ----
__global__ __launch_bounds__(256) void k_scan_add(int* __restrict__ offs,
                                                  const int* __restrict__ bsum) {
  int idx = blockIdx.x * 256 + threadIdx.x;
  if (idx < N_NODES) offs[idx] += bsum[blockIdx.x];
}

// ---- CSR build: scatter (src,eid) into dst order (8B per edge) ----
__global__ __launch_bounds__(256) void k_fill(const int* __restrict__ ei,
                                              const int* __restrict__ offs,
                                              int* __restrict__ cur,
                                              int2* __restrict__ se) {
  int e = blockIdx.x * 256 + threadIdx.x;
  if (e >= E_EDGES) return;
  int d = ei[E_EDGES + e];
  int p = offs[d] + atomicAdd(&cur[d], 1);
  se[p] = make_int2(ei[e], e);
}

// ---- per-edge score: f16 dot2 edge projection + leaky + dot + reduce ----
__device__ __forceinline__ float fscore16(const half2v* eav,
                                          const half2v* we0h,
                                          const half2v* we1h, float xrx,
                                          float xry, float ax, float ay,
                                          float xlx, float xly) {
  float xe0 = 0.f, xe1 = 0.f;
#pragma unroll
  for (int k = 0; k < 8; ++k) {
#if __has_builtin(__builtin_amdgcn_fdot2)
    xe0 = __builtin_amdgcn_fdot2(eav[k], we0h[k], xe0, false);
    xe1 = __builtin_amdgcn_fdot2(eav[k], we1h[k], xe1, false);
#else
    xe0 += (float)eav[k][0] * (float)we0h[k][0] +
           (float)eav[k][1] * (float)we0h[k][1];
    xe1 += (float)eav[k][0] * (float)we1h[k][0] +
           (float)eav[k][1] * (float)we1h[k][1];
#endif
  }
  float v0 = xlx + xrx + xe0;
  float v1 = xly + xry + xe1;
  v0 = v0 > 0.f ? v0 : NEG_SLOPE * v0;
  v1 = v1 > 0.f ? v1 : NEG_SLOPE * v1;
  float p = v0 * ax + v1 * ay;
  p += __shfl_xor(p, 1);
  p += __shfl_xor(p, 2);
  p += __shfl_xor(p, 4);
  p += __shfl_xor(p, 8);
  return p;
}

// online-softmax update: BRANCHLESS (r10-proven). r11's branchy defer-max
// regressed 105->167us (divergence). Do not reintroduce the branch.
#define UPD(p, xx, xy)              \
  {                                 \
    float mn = fmaxf(m, (p));       \
    float sc = __expf(m - mn);      \
    float pe = __expf((p)-mn);      \
    den = den * sc + pe;            \
    a0 = a0 * sc + pe * (xx);       \
    a1 = a1 * sc + pe * (xy);       \
    m = mn;                         \
  }

// ---- Fused per-dst kernel: PERSISTENT wave-per-node (r13-EXACT, x2) ----
// Saturated: x4 unroll neutral (r14); VALUBusy ~64%; keep lean — no LDS/
// barrier/fused-BN (r11/r12 proved those stall it, 105->158us).
__global__ __launch_bounds__(256, 8) void k_node(
    const unsigned short* __restrict__ xlb,
    const unsigned short* __restrict__ xrb, const int2* __restrict__ se,
    const int4* __restrict__ eah, const float* __restrict__ We,
    const float* __restrict__ att, const int* __restrict__ offs,
    const int* __restrict__ deg, float* __restrict__ out) {
  const int wid = __builtin_amdgcn_readfirstlane(
      (int)((blockIdx.x * 256 + threadIdx.x) >> 6));
  const int lane = threadIdx.x & 63;
  const int c0 = lane * 2;

  // hoist W_e columns as f16 pairs (16 VGPR) and att once per wave
  half2v we0h[8], we1h[8];
#pragma unroll
  for (int j = 0; j < 8; ++j) {
    float2 wa = *(const float2*)(We + (2 * j) * 128 + c0);
    float2 wb = *(const float2*)(We + (2 * j + 1) * 128 + c0);
    we0h[j] = (half2v){(_Float16)wa.x, (_Float16)wb.x};
    we1h[j] = (half2v){(_Float16)wa.y, (_Float16)wb.y};
  }
  float2 aw = *(const float2*)(att + c0);

  for (int d = wid; d < N_NODES; d += NWAVES) {
    const int base = __builtin_amdgcn_readfirstlane(offs[d]);
    const int n = __builtin_amdgcn_readfirstlane(deg[d]);
    unsigned ur = *(const unsigned*)(xrb + (size_t)d * 128 + c0);
    float xrx = b2f_lo(ur), xry = b2f_hi(ur);

    float m = -INFINITY, den = 0.f, a0 = 0.f, a1 = 0.f;
    int i = 0;
    for (; i + 2 <= n; i += 2) {
      int2 q0 = se[base + i];
      int2 q1 = se[base + i + 1];
      int s0 = __builtin_amdgcn_readfirstlane(q0.x);
      int s1 = __builtin_amdgcn_readfirstlane(q1.x);
      int e0 = __builtin_amdgcn_readfirstlane(q0.y);
      int e1 = __builtin_amdgcn_readfirstlane(q1.y);
      union {
        int4 q[4];
        half2v h[16];
      } u;
      u.q[0] = eah[(size_t)e0 * 2];
      u.q[1] = eah[(size_t)e0 * 2 + 1];
      u.q[2] = eah[(size_t)e1 * 2];
      u.q[3] = eah[(size_t)e1 * 2 + 1];
      unsigned uA = *(const unsigned*)(xlb + (size_t)s0 * 128 + c0);
      unsigned uB = *(const unsigned*)(xlb + (size_t)s1 * 128 + c0);
      float xAx = b2f_lo(uA), xAy = b2f_hi(uA);
      float xBx = b2f_lo(uB), xBy = b2f_hi(uB);
      float pA = fscore16(u.h, we0h, we1h, xrx, xry, aw.x, aw.y, xAx, xAy);
      float pB =
          fscore16(u.h + 8, we0h, we1h, xrx, xry, aw.x, aw.y, xBx, xBy);
      UPD(pA, xAx, xAy);
      UPD(pB, xBx, xBy);
    }
    if (i < n) {
      int2 q = se[base + i];
      int s0 = __builtin_amdgcn_readfirstlane(q.x);
      int e0 = __builtin_amdgcn_readfirstlane(q.y);
      union {
        int4 q[2];
        half2v h[8];
      } u;
      u.q[0] = eah[(size_t)e0 * 2];
      u.q[1] = eah[(size_t)e0 * 2 + 1];
      unsigned uv = *(const unsigned*)(xlb + (size_t)s0 * 128 + c0);
      float xx = b2f_lo(uv), xy = b2f_hi(uv);
      float p = fscore16(u.h, we0h, we1h, xrx, xry, aw.x, aw.y, xx, xy);
      UPD(p, xx, xy);
    }

    float inv = (n > 0) ? 1.f / den : 0.f;
    float2 o;
    o.x = a0 * inv;
    o.y = a1 * inv;
    *(float2*)(out + (size_t)d * 128 + c0) = o;
  }
}

// ---- BN batch stats: float4 reads + LDS reduce, few global atomics ----
__global__ __launch_bounds__(256) void k_bnstat(const float* __restrict__ out,
                                                float* __restrict__ bnsum,
                                                float* __restrict__ bnsq) {
  __shared__ float ls[256][4];
  __shared__ float lq[256][4];
  int t = threadIdx.x;
  int cg = t & 31;  // channel group -> channels 4*cg..4*cg+3
  int rg = t >> 5;  // row group 0..7
  float s0 = 0, s1 = 0, s2 = 0, s3 = 0, q0 = 0, q1 = 0, q2 = 0, q3 = 0;
  for (int r = blockIdx.x * 8 + rg; r < N_NODES; r += gridDim.x * 8) {
    float4 v = ((const float4*)out)[(size_t)r * 32 + cg];
    s0 += v.x; s1 += v.y; s2 += v.z; s3 += v.w;
    q0 += v.x * v.x; q1 += v.y * v.y; q2 += v.z * v.z; q3 += v.w * v.w;
  }
  ls[t][0] = s0; ls[t][1] = s1; ls[t][2] = s2; ls[t][3] = s3;
  lq[t][0] = q0; lq[t][1] = q1; lq[t][2] = q2; lq[t][3] = q3;
  __syncthreads();
  if (t < 32) {
#pragma unroll
    for (int g = 1; g < 8; ++g) {
#pragma unroll
      for (int i = 0; i < 4; ++i) {
        ls[t][i] += ls[g * 32 + t][i];
        lq[t][i] += lq[g * 32 + t][i];
      }
    }
#pragma unroll
    for (int i = 0; i < 4; ++i) {
      unsafeAtomicAdd(bnsum + 4 * t + i, ls[t][i]);
      unsafeAtomicAdd(bnsq + 4 * t + i, lq[t][i]);
    }
  }
}

// ---- BN apply + ELU + residual (scale/shift recomputed per block) ----
__global__ __launch_bounds__(256) void k_final(
    const float* __restrict__ agg, const float* __restrict__ x,
    const float* __restrict__ bnsum, const float* __restrict__ bnsq,
    const float* __restrict__ gamma, const float* __restrict__ beta,
    float* __restrict__ out) {
  __shared__ __align__(16) float ssc[128];
  __shared__ __align__(16) float ssh[128];
  int t = threadIdx.x;
  if (t < 128) {
    float mu = bnsum[t] * (1.0f / N_NODES);
    float var = bnsq[t] * (1.0f / N_NODES) - mu * mu;
    float sc = gamma[t] * rsqrtf(var + BN_EPS);
    ssc[t] = sc;
    ssh[t] = beta[t] - mu * sc;
  }
  __syncthreads();
  int i4 = blockIdx.x * 256 + t;
  if (i4 >= N_NODES * 32) return;
  int cbase = (i4 * 4) & 127;
  float4 v = ((const float4*)agg)[i4];
  float4 xv = ((const float4*)x)[i4];
  float4 sc = *(const float4*)(ssc + cbase);
  float4 sh = *(const float4*)(ssh + cbase);
  float r0 = v.x * sc.x + sh.x;
  float r1 = v.y * sc.y + sh.y;
  float r2 = v.z * sc.z + sh.z;
  float r3 = v.w * sc.w + sh.w;
  r0 = r0 > 0.f ? r0 : expm1f(r0);
  r1 = r1 > 0.f ? r1 : expm1f(r1);
  r2 = r2 > 0.f ? r2 : expm1f(r2);
  r3 = r3 > 0.f ? r3 : expm1f(r3);
  float4 o;
  o.x = r0 + xv.x; o.y = r1 + xv.y; o.z = r2 + xv.z; o.w = r3 + xv.w;
  ((float4*)out)[i4] = o;
}

extern "C" void kernel_launch(void* const* d_in, const int* in_sizes, int n_in,
                              void* d_out, int out_size, void* d_ws,
                              size_t ws_size, hipStream_t stream) {
  const float* x = (const float*)d_in[0];
  const int* ei = (const int*)d_in[1];
  const float* ea = (const float*)d_in[2];
  const float* Wl = (const float*)d_in[3];
  const float* Wr = (const float*)d_in[4];
  const float* We = (const float*)d_in[5];
  const float* att = (const float*)d_in[6];
  // d_in[7] = bias: cancels inside BatchNorm (per-channel constant) -> unused
  const float* gamma = (const float*)d_in[8];
  const float* beta = (const float*)d_in[9];
  float* out = (float*)d_out;

  unsigned short* xlb = (unsigned short*)d_ws;            // N*128 bf16 (12.8M)
  unsigned short* xrb = xlb + (size_t)N_NODES * 128;      // N*128 bf16 (12.8M)
  int* deg = (int*)(xrb + (size_t)N_NODES * 128);         // 50k
  int* offs = deg + N_NODES;                              // 50k
  int* cur = offs + N_NODES;                              // 50k
  int* bsum = cur + N_NODES;                              // 256
  int2* se = (int2*)(bsum + 256);                         // E int2 (6.4M)
  int4* eah = (int4*)(se + E_EDGES);                      // E*32B f16 (25.6M)
  float* bnsum = (float*)(eah + (size_t)E_EDGES * 2);     // 128
  float* bnsq = bnsum + 128;                              // 128

  // zero deg/offs/cur (contiguous) + BN accumulators before any atomics
  hipMemsetAsync(deg, 0, 3 * N_NODES * sizeof(int), stream);
  hipMemsetAsync(bnsum, 0, 2 * 128 * sizeof(float), stream);

  k_projcnt<<<NB_PROJ + NB_CNT, 256, 0, stream>>>(x, Wl, Wr, xlb, xrb, ei, ea,
                                                  deg, eah);
  k_scan_blk<<<NB_SCAN, 256, 0, stream>>>(deg, offs, bsum);
  k_scan_top<<<1, 256, 0, stream>>>(bsum);
  k_scan_add<<<NB_SCAN, 256, 0, stream>>>(offs, bsum);
  k_fill<<<(E_EDGES + 255) / 256, 256, 0, stream>>>(ei, offs, cur, se);
  k_node<<<NWAVES / 4, 256, 0, stream>>>(xlb, xrb, se, eah, We, att, offs,
                                         deg, out);
  k_bnstat<<<256, 256, 0, stream>>>(out, bnsum, bnsq);
  k_final<<<(N_NODES * 32 + 255) / 256, 256, 0, stream>>>(out, x, bnsum, bnsq,
                                                          gamma, beta, out);
}